// Round 23
// baseline (570.254 us; speedup 1.0000x reference)
//
#include <hip/hip_runtime.h>

#define HID 16
#define OUTC 4
#define G 64             // nodes per agg block
#define SBSH 8           // 256 nodes per partition/sort bucket
#define SBN 256          // nodes per sort bucket
#define CAP 21504        // LDS record buffer per sort bucket (covers nc=256 padding)
#define PHSH 16          // src-phase granule: 65536 nodes = 4MB of mS (per-XCD L2)
#define SUBK 8           // bins per node (>= nphase)
#define KB (SBN * SUBK)  // 2048 sort bins
#define PBLK 512         // threads per partition-pass block
#define NPB_MAX 800      // buckets for unsplit k_cnt (need 782)
#define NPB_H 400        // buckets per parity half in k_part (need 391)
#define STCAP 46         // LDS stage depth per bucket
#define STP 47           // padded stride (odd, coprime with 32 -> conflict-free)
#define EPB 16           // edges per thread per staging pass
#define EPP (PBLK * EPB) // 8192 edges per staging pass
#define SENT 0xFFFFFFFFu

__device__ __forceinline__ float relu(float v) { return v > 0.f ? v : 0.f; }

// ---- Pass A: per-(bucket,chunk) counts (unsplit), PADDED to 16 ----
__global__ void k_cnt(const int* __restrict__ dst, int* __restrict__ cnt,
                      int E, int nsb, int nc, int ncsh) {
    __shared__ int lc[NPB_MAX];
    for (int i = threadIdx.x; i < nsb; i += PBLK) lc[i] = 0;
    __syncthreads();
    int c = blockIdx.x;
    int chunk = (E + nc - 1) / nc;
    int lo = c * chunk, hi = lo + chunk < E ? lo + chunk : E;
    for (int i = lo + threadIdx.x; i < hi; i += PBLK * 4) {
#pragma unroll
        for (int u = 0; u < 4; ++u) {
            int ii = i + u * PBLK;
            if (ii < hi) atomicAdd(lc + (dst[ii] >> SBSH), 1);
        }
    }
    __syncthreads();
    for (int b = threadIdx.x; b < nsb; b += PBLK)
        cnt[(b << ncsh) + c] = (lc[b] + 15) & ~15;      // padded cell size
}

// ---- hierarchical exclusive scan over cnt[nsb*nc] (padded counts) ----
__global__ void k_scanA(int* __restrict__ a, int* __restrict__ bsum, int L) {
    __shared__ int s[1024];
    int i = blockIdx.x * 1024 + threadIdx.x;
    int v = (i < L) ? a[i] : 0;
    s[threadIdx.x] = v; __syncthreads();
    for (int off = 1; off < 1024; off <<= 1) {
        int t = (threadIdx.x >= (unsigned)off) ? s[threadIdx.x - off] : 0;
        __syncthreads();
        s[threadIdx.x] += t;
        __syncthreads();
    }
    if (i < L) a[i] = s[threadIdx.x] - v;               // block-local exclusive
    if (threadIdx.x == 1023) bsum[blockIdx.x] = s[1023];
}

__global__ void k_scanB(int* __restrict__ bsum, int SB) {
    __shared__ int s[1024];
    int carry = 0;
    for (int base = 0; base < SB; base += 1024) {
        int idx = base + threadIdx.x;
        int v = (idx < SB) ? bsum[idx] : 0;
        s[threadIdx.x] = v; __syncthreads();
        for (int off = 1; off < 1024; off <<= 1) {
            int t = (threadIdx.x >= (unsigned)off) ? s[threadIdx.x - off] : 0;
            __syncthreads();
            s[threadIdx.x] += t;
            __syncthreads();
        }
        if (idx < SB) bsum[idx] = carry + s[threadIdx.x] - v;   // exclusive
        carry += s[1023];
        __syncthreads();
    }
    if (threadIdx.x == 0) bsum[SB] = carry;             // grand total (padded)
}

__global__ void k_scanC(int* __restrict__ a, const int* __restrict__ bsum,
                        int* __restrict__ bOff, int L, int nsb, int SB,
                        int nc, int ncsh) {
    int i = blockIdx.x * 1024 + threadIdx.x;
    if (i < L) {
        int v = a[i] + bsum[blockIdx.x];
        a[i] = v;
        if ((i & (nc - 1)) == 0) bOff[i >> ncsh] = v;
    }
    if (blockIdx.x == 0 && threadIdx.x == 0) bOff[nsb] = bsum[SB];
}

// ---- Pass B: parity-split partition; cooperative coalesced line flush ----
__global__ void __launch_bounds__(PBLK) k_part(const int* __restrict__ src,
                                               const int* __restrict__ dst,
                                               const int* __restrict__ cnt,
                                               unsigned int* __restrict__ rec,
                                               int E, int nsb, int nc, int ncsh) {
    __shared__ unsigned int stage[NPB_H * STP];         // stride 47 conflict-free
    __shared__ int scnt[NPB_H];
    __shared__ int gcur[NPB_H];
    int c = blockIdx.x >> 1, h = blockIdx.x & 1;
    int nh = (nsb - h + 1) >> 1;
    for (int bh = threadIdx.x; bh < nh; bh += PBLK) {
        scnt[bh] = 0;
        gcur[bh] = cnt[((bh * 2 + h) << ncsh) + c];     // padded global offset
    }
    __syncthreads();
    int chunk = (E + nc - 1) / nc;
    int lo = c * chunk, hi = lo + chunk < E ? lo + chunk : E;
    int g4 = threadIdx.x >> 2, r4 = threadIdx.x & 3;
    for (int base = lo; base < hi; base += EPP) {
#pragma unroll 4
        for (int k = 0; k < EPB; ++k) {
            int i = base + k * PBLK + threadIdx.x;
            if (i < hi) {
                int d = dst[i], s = src[i];
                int b = d >> SBSH;
                if ((b & 1) == h) {
                    int bh = b >> 1;
                    int pos = atomicAdd(scnt + bh, 1);
                    if (pos < STCAP)
                        stage[bh * STP + pos] = (unsigned int)s | ((unsigned int)(d & (SBN - 1)) << 18);
                }
            }
        }
        __syncthreads();
        for (int bh = g4; bh < nh; bh += PBLK / 4) {
            int n = scnt[bh];
            int f = n & ~15;
            if (f > 0) {
                int gc = gcur[bh];
                for (int j = 0; j < f; j += 16) {
                    const unsigned int* sp = &stage[bh * STP + j] + r4 * 4;
                    ((uint4*)&rec[gc + j])[r4] = make_uint4(sp[0], sp[1], sp[2], sp[3]);
                }
                if (r4 == 0) {
                    gcur[bh] = gc + f;
                    for (int jj = 0; jj < n - f; ++jj)
                        stage[bh * STP + jj] = stage[bh * STP + f + jj];
                    scnt[bh] = n - f;
                }
            }
        }
        __syncthreads();
    }
    for (int bh = threadIdx.x; bh < nh; bh += PBLK) {
        int n = scnt[bh];
        if (n > 0) {
            unsigned int tmp[16];
            for (int j = 0; j < 16; ++j) tmp[j] = (j < n) ? stage[bh * STP + j] : SENT;
            uint4* d4 = (uint4*)&rec[gcur[bh]];
            d4[0] = make_uint4(tmp[0], tmp[1], tmp[2], tmp[3]);
            d4[1] = make_uint4(tmp[4], tmp[5], tmp[6], tmp[7]);
            d4[2] = make_uint4(tmp[8], tmp[9], tmp[10], tmp[11]);
            d4[3] = make_uint4(tmp[12], tmp[13], tmp[14], tmp[15]);
        }
    }
}

// ---- per-bucket counting sort by (dst_local, src>>PHSH); skips sentinels;
//      emits rowp + dinv + FUSED mS1 = x*W1*dinv (one node per thread) ----
__global__ void __launch_bounds__(256) k_sort(const int* __restrict__ bOff,
                                              unsigned int* __restrict__ rec,
                                              float* __restrict__ dinv,
                                              int* __restrict__ rowp,
                                              const float* __restrict__ x,
                                              const float* __restrict__ W1,
                                              float* __restrict__ mS1,
                                              int N, int nsb, int E) {
    __shared__ unsigned int raw[CAP];
    __shared__ int hist[KB], cur[KB];
    __shared__ int s[256];
    __shared__ float w1s[HID];
    int b = blockIdx.x;
    int beg = bOff[b], end = bOff[b + 1];
    int size = end - beg; if (size > CAP) size = CAP;    // LDS guard
    if (threadIdx.x < HID) w1s[threadIdx.x] = W1[threadIdx.x];
    {
        uint4* raw4 = (uint4*)raw;
        const uint4* rec4 = (const uint4*)&rec[beg];
        int size4 = size >> 2;
        for (int i = threadIdx.x; i < size4; i += 256) raw4[i] = rec4[i];
    }
    for (int k = threadIdx.x; k < KB; k += 256) hist[k] = 0;
    __syncthreads();
    for (int i = threadIdx.x; i < size; i += 1024) {
#pragma unroll
        for (int u = 0; u < 4; ++u) {
            int ii = i + u * 256;
            if (ii < size) {
                unsigned int r = raw[ii];
                if (r != SENT) {
                    int key = (int)((r >> 18) << 3) | (int)((r & 0x3FFFF) >> PHSH);
                    atomicAdd(hist + key, 1);
                }
            }
        }
    }
    __syncthreads();
    int t = threadIdx.x;
    int psum = 0;
#pragma unroll
    for (int j = 0; j < SUBK; ++j) psum += hist[t * SUBK + j];
    s[t] = psum; __syncthreads();
    for (int off = 1; off < 256; off <<= 1) {
        int v = (t >= off) ? s[t - off] : 0;
        __syncthreads();
        s[t] += v;
        __syncthreads();
    }
    int ex = s[t] - psum;
    {
        int n = b * SBN + t;
        bool valid = (n < N);
        int running = ex;
#pragma unroll
        for (int j = 0; j < SUBK; ++j) {
            cur[t * SUBK + j] = running;
            if (valid) rowp[(size_t)n * SUBK + j] = beg + running;
            running += hist[t * SUBK + j];
        }
        if (valid) {
            float dv = rsqrtf((float)psum + 1.0f);      // +1 self-loop
            dinv[n] = dv;
            float xv = x[n] * dv;                       // fused k_m1
            float4* m4 = (float4*)&mS1[(size_t)n * HID];
            m4[0] = make_float4(xv * w1s[0], xv * w1s[1], xv * w1s[2], xv * w1s[3]);
            m4[1] = make_float4(xv * w1s[4], xv * w1s[5], xv * w1s[6], xv * w1s[7]);
            m4[2] = make_float4(xv * w1s[8], xv * w1s[9], xv * w1s[10], xv * w1s[11]);
            m4[3] = make_float4(xv * w1s[12], xv * w1s[13], xv * w1s[14], xv * w1s[15]);
        }
    }
    __syncthreads();
    for (int i = t; i < size; i += 1024) {
#pragma unroll
        for (int u = 0; u < 4; ++u) {
            int ii = i + u * 256;
            if (ii < size) {
                unsigned int r = raw[ii];
                if (r != SENT) {
                    int key = (int)((r >> 18) << 3) | (int)((r & 0x3FFFF) >> PHSH);
                    int p = atomicAdd(cur + key, 1);
                    rec[beg + p] = r & 0x3FFFF;
                }
            }
        }
    }
}

// ---- in-place h -> (h @ W2) * dinv ----
__global__ void k_m2(float4* __restrict__ h4, const float* __restrict__ W2,
                     const float* __restrict__ dinv, int N) {
    __shared__ float hs[64][HID + 1];
    __shared__ float w[HID * HID];
    if (threadIdx.x < HID * HID) w[threadIdx.x] = W2[threadIdx.x];
    int idx = blockIdx.x * 256 + threadIdx.x;
    int n = idx >> 2, q = idx & 3;
    int ln = threadIdx.x >> 2;
    if (n < N) {
        float4 v = h4[idx];
        hs[ln][q * 4 + 0] = v.x; hs[ln][q * 4 + 1] = v.y;
        hs[ln][q * 4 + 2] = v.z; hs[ln][q * 4 + 3] = v.w;
    }
    __syncthreads();
    if (n < N) {
        float dn = dinv[n];
        float4 acc = make_float4(0.f, 0.f, 0.f, 0.f);
        const float* hr = hs[ln];
#pragma unroll
        for (int ci = 0; ci < HID; ++ci) {
            float hv = hr[ci];
            const float* wr = w + ci * HID + q * 4;
            acc.x += hv * wr[0]; acc.y += hv * wr[1];
            acc.z += hv * wr[2]; acc.w += hv * wr[3];
        }
        acc.x *= dn; acc.y *= dn; acc.z *= dn; acc.w *= dn;
        h4[idx] = acc;
    }
}

// ---- phased CSR aggregation: spans [p, p+span) as ONE contiguous adj range
//      (phases are contiguous in adj) -> register acc across 2 phases ----
template <int MODE>
__global__ void __launch_bounds__(256) k_aggp(const int* __restrict__ rowp,
                                              const unsigned int* __restrict__ adj,
                                              const float* __restrict__ dinv,
                                              const float4* __restrict__ mS4,
                                              float4* __restrict__ gagg4,
                                              const float4* __restrict__ b4,
                                              const float* __restrict__ Wl,
                                              const float* __restrict__ bl,
                                              float* __restrict__ out,
                                              int N, int p, int span) {
    __shared__ float hs[G][HID + 1];
    __shared__ float wl[HID * OUTC];
    __shared__ float blv[OUTC];
    if (MODE == 2) {
        if (threadIdx.x < HID * OUTC) wl[threadIdx.x] = Wl[threadIdx.x];
        if (threadIdx.x < OUTC) blv[threadIdx.x] = bl[threadIdx.x];
    }
    int dl = threadIdx.x >> 2, q = threadIdx.x & 3;
    int n = blockIdx.x * G + dl;
    if (n < N) {
        int i = rowp[(size_t)n * SUBK + p];
        int end = rowp[(size_t)n * SUBK + p + span];    // contiguous multi-phase range
        float4 acc = (p == 0) ? mS4[n * 4 + q] : gagg4[n * 4 + q];
        for (; i + 8 <= end; i += 8) {
            int s0 = adj[i] * 4 + q, s1 = adj[i + 1] * 4 + q;
            int s2 = adj[i + 2] * 4 + q, s3 = adj[i + 3] * 4 + q;
            int s4 = adj[i + 4] * 4 + q, s5 = adj[i + 5] * 4 + q;
            int s6 = adj[i + 6] * 4 + q, s7 = adj[i + 7] * 4 + q;
            float4 v0 = mS4[s0], v1 = mS4[s1], v2 = mS4[s2], v3 = mS4[s3];
            float4 v4 = mS4[s4], v5 = mS4[s5], v6 = mS4[s6], v7 = mS4[s7];
            acc.x += (v0.x + v1.x + v2.x + v3.x) + (v4.x + v5.x + v6.x + v7.x);
            acc.y += (v0.y + v1.y + v2.y + v3.y) + (v4.y + v5.y + v6.y + v7.y);
            acc.z += (v0.z + v1.z + v2.z + v3.z) + (v4.z + v5.z + v6.z + v7.z);
            acc.w += (v0.w + v1.w + v2.w + v3.w) + (v4.w + v5.w + v6.w + v7.w);
        }
        for (; i + 4 <= end; i += 4) {
            int s0 = adj[i] * 4 + q, s1 = adj[i + 1] * 4 + q;
            int s2 = adj[i + 2] * 4 + q, s3 = adj[i + 3] * 4 + q;
            float4 v0 = mS4[s0], v1 = mS4[s1], v2 = mS4[s2], v3 = mS4[s3];
            acc.x += v0.x + v1.x + v2.x + v3.x;
            acc.y += v0.y + v1.y + v2.y + v3.y;
            acc.z += v0.z + v1.z + v2.z + v3.z;
            acc.w += v0.w + v1.w + v2.w + v3.w;
        }
        for (; i < end; ++i) {
            float4 v = mS4[adj[i] * 4 + q];
            acc.x += v.x; acc.y += v.y; acc.z += v.z; acc.w += v.w;
        }
        if (MODE == 0) {
            gagg4[n * 4 + q] = acc;
        } else {
            float dn = dinv[n];
            float4 bb = b4[q];
            float4 h;
            h.x = relu(acc.x * dn + bb.x);
            h.y = relu(acc.y * dn + bb.y);
            h.z = relu(acc.z * dn + bb.z);
            h.w = relu(acc.w * dn + bb.w);
            if (MODE == 1) {
                gagg4[n * 4 + q] = h;                   // h written in place of gagg
            } else {
                hs[dl][q * 4 + 0] = h.x; hs[dl][q * 4 + 1] = h.y;
                hs[dl][q * 4 + 2] = h.z; hs[dl][q * 4 + 3] = h.w;
            }
        }
    }
    if (MODE == 2) {
        __syncthreads();
        if (n < N) {
            float acc = blv[q];
            const float* hr = hs[dl];
#pragma unroll
            for (int ci = 0; ci < HID; ++ci) acc += hr[ci] * wl[ci * OUTC + q];
            out[n * OUTC + q] = acc;
        }
    }
}

// ---------- launch ----------
static inline size_t alignup(size_t v, size_t a) { return (v + a - 1) & ~(a - 1); }

extern "C" void kernel_launch(void* const* d_in, const int* in_sizes, int n_in,
                              void* d_out, int out_size, void* d_ws, size_t ws_size,
                              hipStream_t stream) {
    const float* x  = (const float*)d_in[0];
    const int* ed   = (const int*)d_in[1];     // int inputs delivered as int32
    const float* W1 = (const float*)d_in[2];
    const float* b1 = (const float*)d_in[3];
    const float* W2 = (const float*)d_in[4];
    const float* b2 = (const float*)d_in[5];
    const float* Wl = (const float*)d_in[6];
    const float* bl = (const float*)d_in[7];
    float* out      = (float*)d_out;

    int N = in_sizes[0];
    int E = in_sizes[1] / 2;
    const int* src = ed;
    const int* dst = ed + E;
    int nsb = (N + SBN - 1) / SBN;             // 782 partition/sort buckets
    int nb64 = (N + G - 1) / G;                // 3125 agg blocks
    int nphase = (N + (1 << PHSH) - 1) >> PHSH;   // 4 (<= SUBK)

    // choose chunk count: prefer 256 if padded rec fits workspace
    int nc = 256, ncsh = 8;
    size_t o = 0;
    float* dinv; int* rowp; int* bsum; int* bOff; unsigned int* rec;
    float* bufA; float* bufB;
    char* w = (char*)d_ws;
    for (int attempt = 0; attempt < 2; ++attempt) {
        int L = nsb * nc;
        int SB = (L + 1023) / 1024;
        size_t Epad = (size_t)E + 15 * (size_t)L;
        o = 0;
        dinv = (float*)(w + o); o = alignup(o + (size_t)N * 4, 64);
        rowp = (int*)(w + o);   o = alignup(o + (size_t)N * SUBK * 4, 64);
        bsum = (int*)(w + o);   o = alignup(o + ((size_t)SB + 1) * 4, 64);
        bOff = (int*)(w + o);   o = alignup(o + ((size_t)nsb + 1) * 4, 64);
        rec  = (unsigned int*)(w + o); o = alignup(o + Epad * 4, 64);
        bufA = (float*)(w + o); o = alignup(o + (size_t)N * HID * 4, 64);
        bufB = (float*)(w + o); o = alignup(o + (size_t)N * HID * 4, 64);
        if (o <= ws_size || nc == 128) break;
        nc = 128; ncsh = 7;                    // fallback sizing
    }
    int L = nsb * nc;
    int SB = (L + 1023) / 1024;
    int* cnt = (int*)bufA;                     // L*4 <= bufA size; dead before k_sort writes mS1

    int blk = 256;

    // CSR build: staged partition + per-bucket sort (fused mS1 emit)
    k_cnt<<<nc, PBLK, 0, stream>>>(dst, cnt, E, nsb, nc, ncsh);
    k_scanA<<<SB, 1024, 0, stream>>>(cnt, bsum, L);
    k_scanB<<<1, 1024, 0, stream>>>(bsum, SB);
    k_scanC<<<SB, 1024, 0, stream>>>(cnt, bsum, bOff, L, nsb, SB, nc, ncsh);
    k_part<<<nc * 2, PBLK, 0, stream>>>(src, dst, cnt, rec, E, nsb, nc, ncsh);
    k_sort<<<nsb, 256, 0, stream>>>(bOff, rec, dinv, rowp, x, W1, bufA, N, nsb, E);

    // layer 1: mS1 in bufA, gagg/h1 in bufB; 2 phases per dispatch
    for (int p = 0; p < nphase; p += 2) {
        int span = (p + 2 <= nphase) ? 2 : 1;
        bool last = (p + span >= nphase);
        if (!last)
            k_aggp<0><<<nb64, blk, 0, stream>>>(rowp, rec, dinv, (const float4*)bufA,
                                                (float4*)bufB, (const float4*)b1,
                                                nullptr, nullptr, nullptr, N, p, span);
        else
            k_aggp<1><<<nb64, blk, 0, stream>>>(rowp, rec, dinv, (const float4*)bufA,
                                                (float4*)bufB, (const float4*)b1,
                                                nullptr, nullptr, nullptr, N, p, span);
    }

    // layer 2: mS2 in bufB (in place), gagg in bufA, readout fused into last dispatch
    k_m2<<<nb64, blk, 0, stream>>>((float4*)bufB, W2, dinv, N);
    for (int p = 0; p < nphase; p += 2) {
        int span = (p + 2 <= nphase) ? 2 : 1;
        bool last = (p + span >= nphase);
        if (!last)
            k_aggp<0><<<nb64, blk, 0, stream>>>(rowp, rec, dinv, (const float4*)bufB,
                                                (float4*)bufA, (const float4*)b2,
                                                nullptr, nullptr, nullptr, N, p, span);
        else
            k_aggp<2><<<nb64, blk, 0, stream>>>(rowp, rec, dinv, (const float4*)bufB,
                                                (float4*)bufA, (const float4*)b2,
                                                Wl, bl, out, N, p, span);
    }
}

// Round 24
// 519.967 us; speedup vs baseline: 1.0967x; 1.0967x over previous
//
#include <hip/hip_runtime.h>

#define HID 16
#define OUTC 4
#define G 64             // nodes per agg block
#define SBSH 8           // 256 nodes per partition/sort bucket
#define SBN 256          // nodes per sort bucket
#define CAP 21504        // LDS record buffer per sort bucket (covers nc=256 padding)
#define PHSH 16          // src-phase granule: 65536 nodes = 4MB of mS (per-XCD L2)
#define SUBK 8           // bins per node (>= nphase)
#define KB (SBN * SUBK)  // 2048 sort bins
#define PBLK 512         // threads per partition-pass block
#define SBLK 512         // threads per sort block (8 waves; LDS-latency hiding)
#define NPB_MAX 800      // buckets for unsplit k_cnt (need 782)
#define NPB_H 400        // buckets per parity half in k_part (need 391)
#define STCAP 46         // LDS stage depth per bucket
#define STP 47           // padded stride (odd, coprime with 32 -> conflict-free)
#define EPB 16           // edges per thread per staging pass
#define EPP (PBLK * EPB) // 8192 edges per staging pass
#define SENT 0xFFFFFFFFu

__device__ __forceinline__ float relu(float v) { return v > 0.f ? v : 0.f; }

// ---- Pass A: per-(bucket,chunk) counts (unsplit), PADDED to 16 ----
__global__ void k_cnt(const int* __restrict__ dst, int* __restrict__ cnt,
                      int E, int nsb, int nc, int ncsh) {
    __shared__ int lc[NPB_MAX];
    for (int i = threadIdx.x; i < nsb; i += PBLK) lc[i] = 0;
    __syncthreads();
    int c = blockIdx.x;
    int chunk = (E + nc - 1) / nc;
    int lo = c * chunk, hi = lo + chunk < E ? lo + chunk : E;
    for (int i = lo + threadIdx.x; i < hi; i += PBLK * 4) {
#pragma unroll
        for (int u = 0; u < 4; ++u) {
            int ii = i + u * PBLK;
            if (ii < hi) atomicAdd(lc + (dst[ii] >> SBSH), 1);
        }
    }
    __syncthreads();
    for (int b = threadIdx.x; b < nsb; b += PBLK)
        cnt[(b << ncsh) + c] = (lc[b] + 15) & ~15;      // padded cell size
}

// ---- hierarchical exclusive scan over cnt[nsb*nc] (padded counts) ----
__global__ void k_scanA(int* __restrict__ a, int* __restrict__ bsum, int L) {
    __shared__ int s[1024];
    int i = blockIdx.x * 1024 + threadIdx.x;
    int v = (i < L) ? a[i] : 0;
    s[threadIdx.x] = v; __syncthreads();
    for (int off = 1; off < 1024; off <<= 1) {
        int t = (threadIdx.x >= (unsigned)off) ? s[threadIdx.x - off] : 0;
        __syncthreads();
        s[threadIdx.x] += t;
        __syncthreads();
    }
    if (i < L) a[i] = s[threadIdx.x] - v;               // block-local exclusive
    if (threadIdx.x == 1023) bsum[blockIdx.x] = s[1023];
}

__global__ void k_scanB(int* __restrict__ bsum, int SB) {
    __shared__ int s[1024];
    int carry = 0;
    for (int base = 0; base < SB; base += 1024) {
        int idx = base + threadIdx.x;
        int v = (idx < SB) ? bsum[idx] : 0;
        s[threadIdx.x] = v; __syncthreads();
        for (int off = 1; off < 1024; off <<= 1) {
            int t = (threadIdx.x >= (unsigned)off) ? s[threadIdx.x - off] : 0;
            __syncthreads();
            s[threadIdx.x] += t;
            __syncthreads();
        }
        if (idx < SB) bsum[idx] = carry + s[threadIdx.x] - v;   // exclusive
        carry += s[1023];
        __syncthreads();
    }
    if (threadIdx.x == 0) bsum[SB] = carry;             // grand total (padded)
}

__global__ void k_scanC(int* __restrict__ a, const int* __restrict__ bsum,
                        int* __restrict__ bOff, int L, int nsb, int SB,
                        int nc, int ncsh) {
    int i = blockIdx.x * 1024 + threadIdx.x;
    if (i < L) {
        int v = a[i] + bsum[blockIdx.x];
        a[i] = v;
        if ((i & (nc - 1)) == 0) bOff[i >> ncsh] = v;
    }
    if (blockIdx.x == 0 && threadIdx.x == 0) bOff[nsb] = bsum[SB];
}

// ---- Pass B: parity-split partition; cooperative coalesced line flush ----
__global__ void __launch_bounds__(PBLK) k_part(const int* __restrict__ src,
                                               const int* __restrict__ dst,
                                               const int* __restrict__ cnt,
                                               unsigned int* __restrict__ rec,
                                               int E, int nsb, int nc, int ncsh) {
    __shared__ unsigned int stage[NPB_H * STP];         // stride 47 conflict-free
    __shared__ int scnt[NPB_H];
    __shared__ int gcur[NPB_H];
    int c = blockIdx.x >> 1, h = blockIdx.x & 1;
    int nh = (nsb - h + 1) >> 1;
    for (int bh = threadIdx.x; bh < nh; bh += PBLK) {
        scnt[bh] = 0;
        gcur[bh] = cnt[((bh * 2 + h) << ncsh) + c];     // padded global offset
    }
    __syncthreads();
    int chunk = (E + nc - 1) / nc;
    int lo = c * chunk, hi = lo + chunk < E ? lo + chunk : E;
    int g4 = threadIdx.x >> 2, r4 = threadIdx.x & 3;
    for (int base = lo; base < hi; base += EPP) {
#pragma unroll 4
        for (int k = 0; k < EPB; ++k) {
            int i = base + k * PBLK + threadIdx.x;
            if (i < hi) {
                int d = dst[i], s = src[i];
                int b = d >> SBSH;
                if ((b & 1) == h) {
                    int bh = b >> 1;
                    int pos = atomicAdd(scnt + bh, 1);
                    if (pos < STCAP)
                        stage[bh * STP + pos] = (unsigned int)s | ((unsigned int)(d & (SBN - 1)) << 18);
                }
            }
        }
        __syncthreads();
        for (int bh = g4; bh < nh; bh += PBLK / 4) {
            int n = scnt[bh];
            int f = n & ~15;
            if (f > 0) {
                int gc = gcur[bh];
                for (int j = 0; j < f; j += 16) {
                    const unsigned int* sp = &stage[bh * STP + j] + r4 * 4;
                    ((uint4*)&rec[gc + j])[r4] = make_uint4(sp[0], sp[1], sp[2], sp[3]);
                }
                if (r4 == 0) {
                    gcur[bh] = gc + f;
                    for (int jj = 0; jj < n - f; ++jj)
                        stage[bh * STP + jj] = stage[bh * STP + f + jj];
                    scnt[bh] = n - f;
                }
            }
        }
        __syncthreads();
    }
    for (int bh = threadIdx.x; bh < nh; bh += PBLK) {
        int n = scnt[bh];
        if (n > 0) {
            unsigned int tmp[16];
            for (int j = 0; j < 16; ++j) tmp[j] = (j < n) ? stage[bh * STP + j] : SENT;
            uint4* d4 = (uint4*)&rec[gcur[bh]];
            d4[0] = make_uint4(tmp[0], tmp[1], tmp[2], tmp[3]);
            d4[1] = make_uint4(tmp[4], tmp[5], tmp[6], tmp[7]);
            d4[2] = make_uint4(tmp[8], tmp[9], tmp[10], tmp[11]);
            d4[3] = make_uint4(tmp[12], tmp[13], tmp[14], tmp[15]);
        }
    }
}

// ---- per-bucket counting sort by (dst_local, src>>PHSH); 512 threads;
//      emits rowp + dinv + FUSED mS1 = x*W1*dinv (node sections on t<256) ----
__global__ void __launch_bounds__(SBLK) k_sort(const int* __restrict__ bOff,
                                               unsigned int* __restrict__ rec,
                                               float* __restrict__ dinv,
                                               int* __restrict__ rowp,
                                               const float* __restrict__ x,
                                               const float* __restrict__ W1,
                                               float* __restrict__ mS1,
                                               int N, int nsb, int E) {
    __shared__ unsigned int raw[CAP];
    __shared__ int hist[KB], cur[KB];
    __shared__ int s[256];
    __shared__ float w1s[HID];
    int b = blockIdx.x;
    int beg = bOff[b], end = bOff[b + 1];
    int size = end - beg; if (size > CAP) size = CAP;    // LDS guard
    if (threadIdx.x < HID) w1s[threadIdx.x] = W1[threadIdx.x];
    {
        uint4* raw4 = (uint4*)raw;
        const uint4* rec4 = (const uint4*)&rec[beg];
        int size4 = size >> 2;
        for (int i = threadIdx.x; i < size4; i += SBLK) raw4[i] = rec4[i];
    }
    for (int k = threadIdx.x; k < KB; k += SBLK) hist[k] = 0;
    __syncthreads();
    for (int i = threadIdx.x; i < size; i += SBLK * 4) {
#pragma unroll
        for (int u = 0; u < 4; ++u) {                   // 4 LDS atomics in flight
            int ii = i + u * SBLK;
            if (ii < size) {
                unsigned int r = raw[ii];
                if (r != SENT) {
                    int key = (int)((r >> 18) << 3) | (int)((r & 0x3FFFF) >> PHSH);
                    atomicAdd(hist + key, 1);
                }
            }
        }
    }
    __syncthreads();
    // exclusive scan over node sums (t<256 own node t's bins; all threads sync)
    int t = threadIdx.x;
    int psum = 0;
    if (t < 256) {
#pragma unroll
        for (int j = 0; j < SUBK; ++j) psum += hist[t * SUBK + j];
        s[t] = psum;
    }
    __syncthreads();
    for (int off = 1; off < 256; off <<= 1) {
        int v = (t < 256 && t >= off) ? s[t - off] : 0;
        __syncthreads();
        if (t < 256) s[t] += v;
        __syncthreads();
    }
    if (t < 256) {
        int ex = s[t] - psum;
        int n = b * SBN + t;
        bool valid = (n < N);
        int running = ex;
#pragma unroll
        for (int j = 0; j < SUBK; ++j) {
            cur[t * SUBK + j] = running;
            if (valid) rowp[(size_t)n * SUBK + j] = beg + running;
            running += hist[t * SUBK + j];
        }
        if (valid) {
            float dv = rsqrtf((float)psum + 1.0f);      // +1 self-loop
            dinv[n] = dv;
            float xv = x[n] * dv;                       // fused k_m1
            float4* m4 = (float4*)&mS1[(size_t)n * HID];
            m4[0] = make_float4(xv * w1s[0], xv * w1s[1], xv * w1s[2], xv * w1s[3]);
            m4[1] = make_float4(xv * w1s[4], xv * w1s[5], xv * w1s[6], xv * w1s[7]);
            m4[2] = make_float4(xv * w1s[8], xv * w1s[9], xv * w1s[10], xv * w1s[11]);
            m4[3] = make_float4(xv * w1s[12], xv * w1s[13], xv * w1s[14], xv * w1s[15]);
        }
    }
    __syncthreads();
    // scatter: reads LDS copy, writes into own global range (no hazard)
    for (int i = threadIdx.x; i < size; i += SBLK * 4) {
#pragma unroll
        for (int u = 0; u < 4; ++u) {
            int ii = i + u * SBLK;
            if (ii < size) {
                unsigned int r = raw[ii];
                if (r != SENT) {
                    int key = (int)((r >> 18) << 3) | (int)((r & 0x3FFFF) >> PHSH);
                    int p = atomicAdd(cur + key, 1);    // LDS int atomic
                    rec[beg + p] = r & 0x3FFFF;         // adjacency = src id
                }
            }
        }
    }
}

// ---- in-place h -> (h @ W2) * dinv ----
__global__ void k_m2(float4* __restrict__ h4, const float* __restrict__ W2,
                     const float* __restrict__ dinv, int N) {
    __shared__ float hs[64][HID + 1];
    __shared__ float w[HID * HID];
    if (threadIdx.x < HID * HID) w[threadIdx.x] = W2[threadIdx.x];
    int idx = blockIdx.x * 256 + threadIdx.x;
    int n = idx >> 2, q = idx & 3;
    int ln = threadIdx.x >> 2;
    if (n < N) {
        float4 v = h4[idx];
        hs[ln][q * 4 + 0] = v.x; hs[ln][q * 4 + 1] = v.y;
        hs[ln][q * 4 + 2] = v.z; hs[ln][q * 4 + 3] = v.w;
    }
    __syncthreads();
    if (n < N) {
        float dn = dinv[n];
        float4 acc = make_float4(0.f, 0.f, 0.f, 0.f);
        const float* hr = hs[ln];
#pragma unroll
        for (int ci = 0; ci < HID; ++ci) {
            float hv = hr[ci];
            const float* wr = w + ci * HID + q * 4;
            acc.x += hv * wr[0]; acc.y += hv * wr[1];
            acc.z += hv * wr[2]; acc.w += hv * wr[3];
        }
        acc.x *= dn; acc.y *= dn; acc.z *= dn; acc.w *= dn;
        h4[idx] = acc;
    }
}

// ---- phased CSR aggregation (4 phases; 4MB window; 8-deep gather ILP) ----
template <int MODE>
__global__ void __launch_bounds__(256) k_aggp(const int* __restrict__ rowp,
                                              const unsigned int* __restrict__ adj,
                                              const float* __restrict__ dinv,
                                              const float4* __restrict__ mS4,
                                              float4* __restrict__ gagg4,
                                              const float4* __restrict__ b4,
                                              const float* __restrict__ Wl,
                                              const float* __restrict__ bl,
                                              float* __restrict__ out,
                                              int N, int p) {
    __shared__ float hs[G][HID + 1];
    __shared__ float wl[HID * OUTC];
    __shared__ float blv[OUTC];
    if (MODE == 2) {
        if (threadIdx.x < HID * OUTC) wl[threadIdx.x] = Wl[threadIdx.x];
        if (threadIdx.x < OUTC) blv[threadIdx.x] = bl[threadIdx.x];
    }
    int dl = threadIdx.x >> 2, q = threadIdx.x & 3;
    int n = blockIdx.x * G + dl;
    if (n < N) {
        int i = rowp[(size_t)n * SUBK + p];
        int end = rowp[(size_t)n * SUBK + p + 1];
        float4 acc = (p == 0) ? mS4[n * 4 + q] : gagg4[n * 4 + q];
        for (; i + 8 <= end; i += 8) {
            int s0 = adj[i] * 4 + q, s1 = adj[i + 1] * 4 + q;
            int s2 = adj[i + 2] * 4 + q, s3 = adj[i + 3] * 4 + q;
            int s4 = adj[i + 4] * 4 + q, s5 = adj[i + 5] * 4 + q;
            int s6 = adj[i + 6] * 4 + q, s7 = adj[i + 7] * 4 + q;
            float4 v0 = mS4[s0], v1 = mS4[s1], v2 = mS4[s2], v3 = mS4[s3];
            float4 v4 = mS4[s4], v5 = mS4[s5], v6 = mS4[s6], v7 = mS4[s7];
            acc.x += (v0.x + v1.x + v2.x + v3.x) + (v4.x + v5.x + v6.x + v7.x);
            acc.y += (v0.y + v1.y + v2.y + v3.y) + (v4.y + v5.y + v6.y + v7.y);
            acc.z += (v0.z + v1.z + v2.z + v3.z) + (v4.z + v5.z + v6.z + v7.z);
            acc.w += (v0.w + v1.w + v2.w + v3.w) + (v4.w + v5.w + v6.w + v7.w);
        }
        for (; i + 4 <= end; i += 4) {
            int s0 = adj[i] * 4 + q, s1 = adj[i + 1] * 4 + q;
            int s2 = adj[i + 2] * 4 + q, s3 = adj[i + 3] * 4 + q;
            float4 v0 = mS4[s0], v1 = mS4[s1], v2 = mS4[s2], v3 = mS4[s3];
            acc.x += v0.x + v1.x + v2.x + v3.x;
            acc.y += v0.y + v1.y + v2.y + v3.y;
            acc.z += v0.z + v1.z + v2.z + v3.z;
            acc.w += v0.w + v1.w + v2.w + v3.w;
        }
        for (; i < end; ++i) {
            float4 v = mS4[adj[i] * 4 + q];
            acc.x += v.x; acc.y += v.y; acc.z += v.z; acc.w += v.w;
        }
        if (MODE == 0) {
            gagg4[n * 4 + q] = acc;
        } else {
            float dn = dinv[n];
            float4 bb = b4[q];
            float4 h;
            h.x = relu(acc.x * dn + bb.x);
            h.y = relu(acc.y * dn + bb.y);
            h.z = relu(acc.z * dn + bb.z);
            h.w = relu(acc.w * dn + bb.w);
            if (MODE == 1) {
                gagg4[n * 4 + q] = h;                   // h written in place of gagg
            } else {
                hs[dl][q * 4 + 0] = h.x; hs[dl][q * 4 + 1] = h.y;
                hs[dl][q * 4 + 2] = h.z; hs[dl][q * 4 + 3] = h.w;
            }
        }
    }
    if (MODE == 2) {
        __syncthreads();
        if (n < N) {
            float acc = blv[q];
            const float* hr = hs[dl];
#pragma unroll
            for (int ci = 0; ci < HID; ++ci) acc += hr[ci] * wl[ci * OUTC + q];
            out[n * OUTC + q] = acc;
        }
    }
}

// ---------- launch ----------
static inline size_t alignup(size_t v, size_t a) { return (v + a - 1) & ~(a - 1); }

extern "C" void kernel_launch(void* const* d_in, const int* in_sizes, int n_in,
                              void* d_out, int out_size, void* d_ws, size_t ws_size,
                              hipStream_t stream) {
    const float* x  = (const float*)d_in[0];
    const int* ed   = (const int*)d_in[1];     // int inputs delivered as int32
    const float* W1 = (const float*)d_in[2];
    const float* b1 = (const float*)d_in[3];
    const float* W2 = (const float*)d_in[4];
    const float* b2 = (const float*)d_in[5];
    const float* Wl = (const float*)d_in[6];
    const float* bl = (const float*)d_in[7];
    float* out      = (float*)d_out;

    int N = in_sizes[0];
    int E = in_sizes[1] / 2;
    const int* src = ed;
    const int* dst = ed + E;
    int nsb = (N + SBN - 1) / SBN;             // 782 partition/sort buckets
    int nb64 = (N + G - 1) / G;                // 3125 agg blocks
    int nphase = (N + (1 << PHSH) - 1) >> PHSH;   // 4 (<= SUBK)

    // choose chunk count: prefer 256 if padded rec fits workspace
    int nc = 256, ncsh = 8;
    size_t o = 0;
    float* dinv; int* rowp; int* bsum; int* bOff; unsigned int* rec;
    float* bufA; float* bufB;
    char* w = (char*)d_ws;
    for (int attempt = 0; attempt < 2; ++attempt) {
        int L = nsb * nc;
        int SB = (L + 1023) / 1024;
        size_t Epad = (size_t)E + 15 * (size_t)L;
        o = 0;
        dinv = (float*)(w + o); o = alignup(o + (size_t)N * 4, 64);
        rowp = (int*)(w + o);   o = alignup(o + (size_t)N * SUBK * 4, 64);
        bsum = (int*)(w + o);   o = alignup(o + ((size_t)SB + 1) * 4, 64);
        bOff = (int*)(w + o);   o = alignup(o + ((size_t)nsb + 1) * 4, 64);
        rec  = (unsigned int*)(w + o); o = alignup(o + Epad * 4, 64);
        bufA = (float*)(w + o); o = alignup(o + (size_t)N * HID * 4, 64);
        bufB = (float*)(w + o); o = alignup(o + (size_t)N * HID * 4, 64);
        if (o <= ws_size || nc == 128) break;
        nc = 128; ncsh = 7;                    // fallback sizing
    }
    int L = nsb * nc;
    int SB = (L + 1023) / 1024;
    int* cnt = (int*)bufA;                     // L*4 <= bufA size; dead before k_sort writes mS1

    int blk = 256;

    // CSR build: staged partition + per-bucket sort (fused mS1 emit)
    k_cnt<<<nc, PBLK, 0, stream>>>(dst, cnt, E, nsb, nc, ncsh);
    k_scanA<<<SB, 1024, 0, stream>>>(cnt, bsum, L);
    k_scanB<<<1, 1024, 0, stream>>>(bsum, SB);
    k_scanC<<<SB, 1024, 0, stream>>>(cnt, bsum, bOff, L, nsb, SB, nc, ncsh);
    k_part<<<nc * 2, PBLK, 0, stream>>>(src, dst, cnt, rec, E, nsb, nc, ncsh);
    k_sort<<<nsb, SBLK, 0, stream>>>(bOff, rec, dinv, rowp, x, W1, bufA, N, nsb, E);

    // layer 1: mS1 in bufA, gagg/h1 in bufB
    for (int p = 0; p < nphase; ++p) {
        if (p < nphase - 1)
            k_aggp<0><<<nb64, blk, 0, stream>>>(rowp, rec, dinv, (const float4*)bufA,
                                                (float4*)bufB, (const float4*)b1,
                                                nullptr, nullptr, nullptr, N, p);
        else
            k_aggp<1><<<nb64, blk, 0, stream>>>(rowp, rec, dinv, (const float4*)bufA,
                                                (float4*)bufB, (const float4*)b1,
                                                nullptr, nullptr, nullptr, N, p);
    }

    // layer 2: mS2 in bufB (in place), gagg in bufA, readout fused into last phase
    k_m2<<<nb64, blk, 0, stream>>>((float4*)bufB, W2, dinv, N);
    for (int p = 0; p < nphase; ++p) {
        if (p < nphase - 1)
            k_aggp<0><<<nb64, blk, 0, stream>>>(rowp, rec, dinv, (const float4*)bufB,
                                                (float4*)bufA, (const float4*)b2,
                                                nullptr, nullptr, nullptr, N, p);
        else
            k_aggp<2><<<nb64, blk, 0, stream>>>(rowp, rec, dinv, (const float4*)bufB,
                                                (float4*)bufA, (const float4*)b2,
                                                Wl, bl, out, N, p);
    }
}

// Round 25
// 514.945 us; speedup vs baseline: 1.1074x; 1.0098x over previous
//
#include <hip/hip_runtime.h>

#define HID 16
#define OUTC 4
#define G 64             // nodes per agg block
#define SBSH 8           // 256 nodes per partition/sort bucket
#define SBN 256          // nodes per sort bucket
#define CAP 21504        // LDS record buffer per sort bucket (covers nc=256 padding)
#define PHSH 16          // src-phase granule: 65536 nodes = 4MB of mS (per-XCD L2)
#define SUBK 8           // bins per node (>= nphase)
#define KB (SBN * SUBK)  // 2048 sort bins
#define PBLK 512         // threads per partition-pass block
#define SBLK 512         // threads per sort block (8 waves; LDS-latency hiding)
#define NPB_MAX 800      // buckets for unsplit k_cnt (need 782)
#define NPB_H 400        // buckets per parity half in k_part (need 391)
#define STCAP 46         // LDS stage depth per bucket
#define STP 47           // padded stride (odd, coprime with 32 -> conflict-free)
#define EPB 16           // edges per thread per staging pass
#define EPP (PBLK * EPB) // 8192 edges per staging pass
#define SENT 0xFFFFFFFFu

__device__ __forceinline__ float relu(float v) { return v > 0.f ? v : 0.f; }

// ---- Pass A: per-(bucket,chunk) counts (unsplit), PADDED to 16 ----
__global__ void k_cnt(const int* __restrict__ dst, int* __restrict__ cnt,
                      int E, int nsb, int nc, int ncsh) {
    __shared__ int lc[NPB_MAX];
    for (int i = threadIdx.x; i < nsb; i += PBLK) lc[i] = 0;
    __syncthreads();
    int c = blockIdx.x;
    int chunk = (E + nc - 1) / nc;
    int lo = c * chunk, hi = lo + chunk < E ? lo + chunk : E;
    for (int i = lo + threadIdx.x; i < hi; i += PBLK * 4) {
#pragma unroll
        for (int u = 0; u < 4; ++u) {
            int ii = i + u * PBLK;
            if (ii < hi) atomicAdd(lc + (dst[ii] >> SBSH), 1);
        }
    }
    __syncthreads();
    for (int b = threadIdx.x; b < nsb; b += PBLK)
        cnt[(b << ncsh) + c] = (lc[b] + 15) & ~15;      // padded cell size
}

// ---- hierarchical exclusive scan over cnt[nsb*nc] (padded counts) ----
__global__ void k_scanA(int* __restrict__ a, int* __restrict__ bsum, int L) {
    __shared__ int s[1024];
    int i = blockIdx.x * 1024 + threadIdx.x;
    int v = (i < L) ? a[i] : 0;
    s[threadIdx.x] = v; __syncthreads();
    for (int off = 1; off < 1024; off <<= 1) {
        int t = (threadIdx.x >= (unsigned)off) ? s[threadIdx.x - off] : 0;
        __syncthreads();
        s[threadIdx.x] += t;
        __syncthreads();
    }
    if (i < L) a[i] = s[threadIdx.x] - v;               // block-local exclusive
    if (threadIdx.x == 1023) bsum[blockIdx.x] = s[1023];
}

__global__ void k_scanB(int* __restrict__ bsum, int SB) {
    __shared__ int s[1024];
    int carry = 0;
    for (int base = 0; base < SB; base += 1024) {
        int idx = base + threadIdx.x;
        int v = (idx < SB) ? bsum[idx] : 0;
        s[threadIdx.x] = v; __syncthreads();
        for (int off = 1; off < 1024; off <<= 1) {
            int t = (threadIdx.x >= (unsigned)off) ? s[threadIdx.x - off] : 0;
            __syncthreads();
            s[threadIdx.x] += t;
            __syncthreads();
        }
        if (idx < SB) bsum[idx] = carry + s[threadIdx.x] - v;   // exclusive
        carry += s[1023];
        __syncthreads();
    }
    if (threadIdx.x == 0) bsum[SB] = carry;             // grand total (padded)
}

__global__ void k_scanC(int* __restrict__ a, const int* __restrict__ bsum,
                        int* __restrict__ bOff, int L, int nsb, int SB,
                        int nc, int ncsh) {
    int i = blockIdx.x * 1024 + threadIdx.x;
    if (i < L) {
        int v = a[i] + bsum[blockIdx.x];
        a[i] = v;
        if ((i & (nc - 1)) == 0) bOff[i >> ncsh] = v;
    }
    if (blockIdx.x == 0 && threadIdx.x == 0) bOff[nsb] = bsum[SB];
}

// ---- Pass B: parity-split partition; cooperative coalesced line flush ----
__global__ void __launch_bounds__(PBLK) k_part(const int* __restrict__ src,
                                               const int* __restrict__ dst,
                                               const int* __restrict__ cnt,
                                               unsigned int* __restrict__ rec,
                                               int E, int nsb, int nc, int ncsh) {
    __shared__ unsigned int stage[NPB_H * STP];         // stride 47 conflict-free
    __shared__ int scnt[NPB_H];
    __shared__ int gcur[NPB_H];
    int c = blockIdx.x >> 1, h = blockIdx.x & 1;
    int nh = (nsb - h + 1) >> 1;
    for (int bh = threadIdx.x; bh < nh; bh += PBLK) {
        scnt[bh] = 0;
        gcur[bh] = cnt[((bh * 2 + h) << ncsh) + c];     // padded global offset
    }
    __syncthreads();
    int chunk = (E + nc - 1) / nc;
    int lo = c * chunk, hi = lo + chunk < E ? lo + chunk : E;
    int g4 = threadIdx.x >> 2, r4 = threadIdx.x & 3;
    for (int base = lo; base < hi; base += EPP) {
#pragma unroll 4
        for (int k = 0; k < EPB; ++k) {
            int i = base + k * PBLK + threadIdx.x;
            if (i < hi) {
                int d = dst[i], s = src[i];
                int b = d >> SBSH;
                if ((b & 1) == h) {
                    int bh = b >> 1;
                    int pos = atomicAdd(scnt + bh, 1);
                    if (pos < STCAP)
                        stage[bh * STP + pos] = (unsigned int)s | ((unsigned int)(d & (SBN - 1)) << 18);
                }
            }
        }
        __syncthreads();
        for (int bh = g4; bh < nh; bh += PBLK / 4) {
            int n = scnt[bh];
            int f = n & ~15;
            if (f > 0) {
                int gc = gcur[bh];
                for (int j = 0; j < f; j += 16) {
                    const unsigned int* sp = &stage[bh * STP + j] + r4 * 4;
                    ((uint4*)&rec[gc + j])[r4] = make_uint4(sp[0], sp[1], sp[2], sp[3]);
                }
                if (r4 == 0) {
                    gcur[bh] = gc + f;
                    for (int jj = 0; jj < n - f; ++jj)
                        stage[bh * STP + jj] = stage[bh * STP + f + jj];
                    scnt[bh] = n - f;
                }
            }
        }
        __syncthreads();
    }
    for (int bh = threadIdx.x; bh < nh; bh += PBLK) {
        int n = scnt[bh];
        if (n > 0) {
            unsigned int tmp[16];
            for (int j = 0; j < 16; ++j) tmp[j] = (j < n) ? stage[bh * STP + j] : SENT;
            uint4* d4 = (uint4*)&rec[gcur[bh]];
            d4[0] = make_uint4(tmp[0], tmp[1], tmp[2], tmp[3]);
            d4[1] = make_uint4(tmp[4], tmp[5], tmp[6], tmp[7]);
            d4[2] = make_uint4(tmp[8], tmp[9], tmp[10], tmp[11]);
            d4[3] = make_uint4(tmp[12], tmp[13], tmp[14], tmp[15]);
        }
    }
}

// ---- per-bucket counting sort by (dst_local, src>>PHSH); 512 threads;
//      emits rowp + dinv + FUSED mS1 = x*W1*dinv (node sections on t<256) ----
__global__ void __launch_bounds__(SBLK) k_sort(const int* __restrict__ bOff,
                                               unsigned int* __restrict__ rec,
                                               float* __restrict__ dinv,
                                               int* __restrict__ rowp,
                                               const float* __restrict__ x,
                                               const float* __restrict__ W1,
                                               float* __restrict__ mS1,
                                               int N, int nsb, int E) {
    __shared__ unsigned int raw[CAP];
    __shared__ int hist[KB], cur[KB];
    __shared__ int s[256];
    __shared__ float w1s[HID];
    int b = blockIdx.x;
    int beg = bOff[b], end = bOff[b + 1];
    int size = end - beg; if (size > CAP) size = CAP;    // LDS guard
    if (threadIdx.x < HID) w1s[threadIdx.x] = W1[threadIdx.x];
    {
        uint4* raw4 = (uint4*)raw;
        const uint4* rec4 = (const uint4*)&rec[beg];
        int size4 = size >> 2;
        for (int i = threadIdx.x; i < size4; i += SBLK) raw4[i] = rec4[i];
    }
    for (int k = threadIdx.x; k < KB; k += SBLK) hist[k] = 0;
    __syncthreads();
    for (int i = threadIdx.x; i < size; i += SBLK * 4) {
#pragma unroll
        for (int u = 0; u < 4; ++u) {                   // 4 LDS atomics in flight
            int ii = i + u * SBLK;
            if (ii < size) {
                unsigned int r = raw[ii];
                if (r != SENT) {
                    int key = (int)((r >> 18) << 3) | (int)((r & 0x3FFFF) >> PHSH);
                    atomicAdd(hist + key, 1);
                }
            }
        }
    }
    __syncthreads();
    // exclusive scan over node sums (t<256 own node t's bins; all threads sync)
    int t = threadIdx.x;
    int psum = 0;
    if (t < 256) {
#pragma unroll
        for (int j = 0; j < SUBK; ++j) psum += hist[t * SUBK + j];
        s[t] = psum;
    }
    __syncthreads();
    for (int off = 1; off < 256; off <<= 1) {
        int v = (t < 256 && t >= off) ? s[t - off] : 0;
        __syncthreads();
        if (t < 256) s[t] += v;
        __syncthreads();
    }
    if (t < 256) {
        int ex = s[t] - psum;
        int n = b * SBN + t;
        bool valid = (n < N);
        int running = ex;
#pragma unroll
        for (int j = 0; j < SUBK; ++j) {
            cur[t * SUBK + j] = running;
            if (valid) rowp[(size_t)n * SUBK + j] = beg + running;
            running += hist[t * SUBK + j];
        }
        if (valid) {
            float dv = rsqrtf((float)psum + 1.0f);      // +1 self-loop
            dinv[n] = dv;
            float xv = x[n] * dv;                       // fused k_m1
            float4* m4 = (float4*)&mS1[(size_t)n * HID];
            m4[0] = make_float4(xv * w1s[0], xv * w1s[1], xv * w1s[2], xv * w1s[3]);
            m4[1] = make_float4(xv * w1s[4], xv * w1s[5], xv * w1s[6], xv * w1s[7]);
            m4[2] = make_float4(xv * w1s[8], xv * w1s[9], xv * w1s[10], xv * w1s[11]);
            m4[3] = make_float4(xv * w1s[12], xv * w1s[13], xv * w1s[14], xv * w1s[15]);
        }
    }
    __syncthreads();
    // scatter: reads LDS copy, writes into own global range (no hazard)
    for (int i = threadIdx.x; i < size; i += SBLK * 4) {
#pragma unroll
        for (int u = 0; u < 4; ++u) {
            int ii = i + u * SBLK;
            if (ii < size) {
                unsigned int r = raw[ii];
                if (r != SENT) {
                    int key = (int)((r >> 18) << 3) | (int)((r & 0x3FFFF) >> PHSH);
                    int p = atomicAdd(cur + key, 1);    // LDS int atomic
                    rec[beg + p] = r & 0x3FFFF;         // adjacency = src id
                }
            }
        }
    }
}

// ---- phased CSR aggregation (4 phases; 4MB window; 8-deep gather ILP)
//      MODE 0: partial->gagg.  MODE 1: layer-1 epilogue FUSED with k_m2:
//      writes mS2=(relu(acc*dinv+b1)@W2)*dinv.  MODE 2: layer-2 epilogue+readout. ----
template <int MODE>
__global__ void __launch_bounds__(256) k_aggp(const int* __restrict__ rowp,
                                              const unsigned int* __restrict__ adj,
                                              const float* __restrict__ dinv,
                                              const float4* __restrict__ mS4,
                                              float4* __restrict__ gagg4,
                                              const float4* __restrict__ b4,
                                              const float* __restrict__ Wx,   // MODE1: W2, MODE2: Wl
                                              const float* __restrict__ bl,
                                              float* __restrict__ out,
                                              int N, int p) {
    __shared__ float hs[G][HID + 1];
    __shared__ float wx[HID * HID];                     // MODE1: 256 used; MODE2: 64 used
    __shared__ float blv[OUTC];
    if (MODE == 1) {
        if (threadIdx.x < HID * HID) wx[threadIdx.x] = Wx[threadIdx.x];
    }
    if (MODE == 2) {
        if (threadIdx.x < HID * OUTC) wx[threadIdx.x] = Wx[threadIdx.x];
        if (threadIdx.x < OUTC) blv[threadIdx.x] = bl[threadIdx.x];
    }
    int dl = threadIdx.x >> 2, q = threadIdx.x & 3;
    int n = blockIdx.x * G + dl;
    float dn = 0.f;
    if (n < N) {
        int i = rowp[(size_t)n * SUBK + p];
        int end = rowp[(size_t)n * SUBK + p + 1];
        float4 acc = (p == 0) ? mS4[n * 4 + q] : gagg4[n * 4 + q];
        for (; i + 8 <= end; i += 8) {
            int s0 = adj[i] * 4 + q, s1 = adj[i + 1] * 4 + q;
            int s2 = adj[i + 2] * 4 + q, s3 = adj[i + 3] * 4 + q;
            int s4 = adj[i + 4] * 4 + q, s5 = adj[i + 5] * 4 + q;
            int s6 = adj[i + 6] * 4 + q, s7 = adj[i + 7] * 4 + q;
            float4 v0 = mS4[s0], v1 = mS4[s1], v2 = mS4[s2], v3 = mS4[s3];
            float4 v4 = mS4[s4], v5 = mS4[s5], v6 = mS4[s6], v7 = mS4[s7];
            acc.x += (v0.x + v1.x + v2.x + v3.x) + (v4.x + v5.x + v6.x + v7.x);
            acc.y += (v0.y + v1.y + v2.y + v3.y) + (v4.y + v5.y + v6.y + v7.y);
            acc.z += (v0.z + v1.z + v2.z + v3.z) + (v4.z + v5.z + v6.z + v7.z);
            acc.w += (v0.w + v1.w + v2.w + v3.w) + (v4.w + v5.w + v6.w + v7.w);
        }
        for (; i + 4 <= end; i += 4) {
            int s0 = adj[i] * 4 + q, s1 = adj[i + 1] * 4 + q;
            int s2 = adj[i + 2] * 4 + q, s3 = adj[i + 3] * 4 + q;
            float4 v0 = mS4[s0], v1 = mS4[s1], v2 = mS4[s2], v3 = mS4[s3];
            acc.x += v0.x + v1.x + v2.x + v3.x;
            acc.y += v0.y + v1.y + v2.y + v3.y;
            acc.z += v0.z + v1.z + v2.z + v3.z;
            acc.w += v0.w + v1.w + v2.w + v3.w;
        }
        for (; i < end; ++i) {
            float4 v = mS4[adj[i] * 4 + q];
            acc.x += v.x; acc.y += v.y; acc.z += v.z; acc.w += v.w;
        }
        if (MODE == 0) {
            gagg4[n * 4 + q] = acc;
        } else {
            dn = dinv[n];
            float4 bb = b4[q];
            hs[dl][q * 4 + 0] = relu(acc.x * dn + bb.x);
            hs[dl][q * 4 + 1] = relu(acc.y * dn + bb.y);
            hs[dl][q * 4 + 2] = relu(acc.z * dn + bb.z);
            hs[dl][q * 4 + 3] = relu(acc.w * dn + bb.w);
        }
    }
    if (MODE == 1) {
        __syncthreads();
        if (n < N) {   // fused k_m2: mS2 quad = (h @ W2)[q*4..q*4+3] * dinv
            const float* hr = hs[dl];
            float m0 = 0.f, m1 = 0.f, m2 = 0.f, m3 = 0.f;
#pragma unroll
            for (int ci = 0; ci < HID; ++ci) {
                float hv = hr[ci];
                const float* wr = wx + ci * HID + q * 4;
                m0 += hv * wr[0]; m1 += hv * wr[1];
                m2 += hv * wr[2]; m3 += hv * wr[3];
            }
            gagg4[n * 4 + q] = make_float4(m0 * dn, m1 * dn, m2 * dn, m3 * dn);
        }
    }
    if (MODE == 2) {
        __syncthreads();
        if (n < N) {   // readout: thread -> (node dl, out-channel q)
            float acc = blv[q];
            const float* hr = hs[dl];
#pragma unroll
            for (int ci = 0; ci < HID; ++ci) acc += hr[ci] * wx[ci * OUTC + q];
            out[n * OUTC + q] = acc;
        }
    }
}

// ---------- launch ----------
static inline size_t alignup(size_t v, size_t a) { return (v + a - 1) & ~(a - 1); }

extern "C" void kernel_launch(void* const* d_in, const int* in_sizes, int n_in,
                              void* d_out, int out_size, void* d_ws, size_t ws_size,
                              hipStream_t stream) {
    const float* x  = (const float*)d_in[0];
    const int* ed   = (const int*)d_in[1];     // int inputs delivered as int32
    const float* W1 = (const float*)d_in[2];
    const float* b1 = (const float*)d_in[3];
    const float* W2 = (const float*)d_in[4];
    const float* b2 = (const float*)d_in[5];
    const float* Wl = (const float*)d_in[6];
    const float* bl = (const float*)d_in[7];
    float* out      = (float*)d_out;

    int N = in_sizes[0];
    int E = in_sizes[1] / 2;
    const int* src = ed;
    const int* dst = ed + E;
    int nsb = (N + SBN - 1) / SBN;             // 782 partition/sort buckets
    int nb64 = (N + G - 1) / G;                // 3125 agg blocks
    int nphase = (N + (1 << PHSH) - 1) >> PHSH;   // 4 (<= SUBK)

    // choose chunk count: prefer 256 if padded rec fits workspace
    int nc = 256, ncsh = 8;
    size_t o = 0;
    float* dinv; int* rowp; int* bsum; int* bOff; unsigned int* rec;
    float* bufA; float* bufB;
    char* w = (char*)d_ws;
    for (int attempt = 0; attempt < 2; ++attempt) {
        int L = nsb * nc;
        int SB = (L + 1023) / 1024;
        size_t Epad = (size_t)E + 15 * (size_t)L;
        o = 0;
        dinv = (float*)(w + o); o = alignup(o + (size_t)N * 4, 64);
        rowp = (int*)(w + o);   o = alignup(o + (size_t)N * SUBK * 4, 64);
        bsum = (int*)(w + o);   o = alignup(o + ((size_t)SB + 1) * 4, 64);
        bOff = (int*)(w + o);   o = alignup(o + ((size_t)nsb + 1) * 4, 64);
        rec  = (unsigned int*)(w + o); o = alignup(o + Epad * 4, 64);
        bufA = (float*)(w + o); o = alignup(o + (size_t)N * HID * 4, 64);
        bufB = (float*)(w + o); o = alignup(o + (size_t)N * HID * 4, 64);
        if (o <= ws_size || nc == 128) break;
        nc = 128; ncsh = 7;                    // fallback sizing
    }
    int L = nsb * nc;
    int SB = (L + 1023) / 1024;
    int* cnt = (int*)bufA;                     // L*4 <= bufA size; dead before k_sort writes mS1

    int blk = 256;

    // CSR build: staged partition + per-bucket sort (fused mS1 emit)
    k_cnt<<<nc, PBLK, 0, stream>>>(dst, cnt, E, nsb, nc, ncsh);
    k_scanA<<<SB, 1024, 0, stream>>>(cnt, bsum, L);
    k_scanB<<<1, 1024, 0, stream>>>(bsum, SB);
    k_scanC<<<SB, 1024, 0, stream>>>(cnt, bsum, bOff, L, nsb, SB, nc, ncsh);
    k_part<<<nc * 2, PBLK, 0, stream>>>(src, dst, cnt, rec, E, nsb, nc, ncsh);
    k_sort<<<nsb, SBLK, 0, stream>>>(bOff, rec, dinv, rowp, x, W1, bufA, N, nsb, E);

    // layer 1: mS1 in bufA, gagg in bufB; last phase fuses h+k_m2 -> bufB = mS2
    for (int p = 0; p < nphase; ++p) {
        if (p < nphase - 1)
            k_aggp<0><<<nb64, blk, 0, stream>>>(rowp, rec, dinv, (const float4*)bufA,
                                                (float4*)bufB, (const float4*)b1,
                                                nullptr, nullptr, nullptr, N, p);
        else
            k_aggp<1><<<nb64, blk, 0, stream>>>(rowp, rec, dinv, (const float4*)bufA,
                                                (float4*)bufB, (const float4*)b1,
                                                W2, nullptr, nullptr, N, p);
    }

    // layer 2: mS2 in bufB, gagg in bufA, readout fused into last phase
    for (int p = 0; p < nphase; ++p) {
        if (p < nphase - 1)
            k_aggp<0><<<nb64, blk, 0, stream>>>(rowp, rec, dinv, (const float4*)bufB,
                                                (float4*)bufA, (const float4*)b2,
                                                nullptr, nullptr, nullptr, N, p);
        else
            k_aggp<2><<<nb64, blk, 0, stream>>>(rowp, rec, dinv, (const float4*)bufB,
                                                (float4*)bufA, (const float4*)b2,
                                                Wl, bl, out, N, p);
    }
}